// Round 12
// baseline (41.513 us; speedup 1.0000x reference)
//
#include <hip/hip_runtime.h>

#define DD 256
#define TQ 512
#define TK 1024
#define NG 64            // d-quads (256/4)
#define C2 2.88539008177792681472f   // 2*log2(e)

typedef short bf16x8 __attribute__((ext_vector_type(8)));
typedef float f32x4  __attribute__((ext_vector_type(4)));

__device__ __forceinline__ float fexp2(float x){ return __builtin_amdgcn_exp2f(x); }
__device__ __forceinline__ float frcp (float x){ return __builtin_amdgcn_rcpf(x); }
__device__ __forceinline__ short rne_bf16(float x){
    union { float f; unsigned u; } v; v.f = x;
    unsigned r = v.u + 0x7FFFu + ((v.u >> 16) & 1u);
    return (short)(r >> 16);
}

// -------- proj via MFMA (R11-validated layout), now storing TRANSPOSED E --------
// EqT[d][q] (512-stride), EkT[d][k] (1024-stride); E = exp2(C2 * (X @ W^T))
__global__ __launch_bounds__(256) void proj_mfma_kernel(
    const float* __restrict__ query, const float* __restrict__ key,
    const float* __restrict__ Wq, const float* __restrict__ Wk,
    float* __restrict__ eqT, float* __restrict__ ekT)
{
    const int w = threadIdx.x >> 6, l = threadIdx.x & 63;
    int i = blockIdx.x * 4 + w;
    const float* X; const float* W; float* outT; int NT;
    if (i < 512) { X = query; W = Wq; outT = eqT; NT = TQ; }
    else { i -= 512; X = key; W = Wk; outT = ekT; NT = TK; }
    const int rt = i >> 4, ct = i & 15;
    const int lr = l & 15, kg = (l >> 4) * 8;
    const float* Xp = X + (rt * 16 + lr) * DD + kg;
    const float* Wp = W + (ct * 16 + lr) * DD + kg;

    f32x4 acc = {0.f, 0.f, 0.f, 0.f};
    #pragma unroll
    for (int k0 = 0; k0 < DD; k0 += 32) {
        float4 xa = *(const float4*)&Xp[k0];
        float4 xb = *(const float4*)&Xp[k0 + 4];
        float4 wa = *(const float4*)&Wp[k0];
        float4 wb = *(const float4*)&Wp[k0 + 4];
        bf16x8 af, bf;
        af[0] = rne_bf16(xa.x); af[1] = rne_bf16(xa.y);
        af[2] = rne_bf16(xa.z); af[3] = rne_bf16(xa.w);
        af[4] = rne_bf16(xb.x); af[5] = rne_bf16(xb.y);
        af[6] = rne_bf16(xb.z); af[7] = rne_bf16(xb.w);
        bf[0] = rne_bf16(wa.x); bf[1] = rne_bf16(wa.y);
        bf[2] = rne_bf16(wa.z); bf[3] = rne_bf16(wa.w);
        bf[4] = rne_bf16(wb.x); bf[5] = rne_bf16(wb.y);
        bf[6] = rne_bf16(wb.z); bf[7] = rne_bf16(wb.w);
        acc = __builtin_amdgcn_mfma_f32_16x16x32_bf16(af, bf, acc, 0, 0, 0);
    }
    // C: row(token) = rt*16 + (l>>4)*4 + r, col(d) = ct*16 + lr  -> store E^T[d][token]
    const int orow = rt * 16 + (l >> 4) * 4;
    const int ocol = ct * 16 + lr;
    float4 st = make_float4(fexp2(C2 * acc[0]), fexp2(C2 * acc[1]),
                            fexp2(C2 * acc[2]), fexp2(C2 * acc[3]));
    *(float4*)&outT[ocol * NT + orow] = st;
}

// -------- featurize: per (token, quad g) build 16 subset-product features --------
// p[S] = prod_{i in S} E[4g+i]; den-side stores p; q-side also stores c_S * p_S
// with c_S = sum_{j not in S} v[4g+j].  Layout: out[(token*NG + g)*16 + S] bf16.
__global__ __launch_bounds__(256) void featurize_kernel(
    const float* __restrict__ ET, const float* __restrict__ vw,
    unsigned short* __restrict__ outd, unsigned short* __restrict__ outn,
    int NT, int qside)
{
    const int token = blockIdx.x * 256 + threadIdx.x;
    const int g = blockIdx.y;
    float E0 = ET[(4*g+0)*NT + token];
    float E1 = ET[(4*g+1)*NT + token];
    float E2 = ET[(4*g+2)*NT + token];
    float E3 = ET[(4*g+3)*NT + token];
    float p[16];
    p[0]=1.f;   p[1]=E0;      p[2]=E1;      p[3]=E0*E1;
    p[4]=E2;    p[5]=E0*E2;   p[6]=E1*E2;   p[7]=p[3]*E2;
    p[8]=E3;    p[9]=E0*E3;   p[10]=E1*E3;  p[11]=p[3]*E3;
    p[12]=E2*E3;p[13]=p[5]*E3;p[14]=p[6]*E3;p[15]=p[7]*E3;

    const int base = (token * NG + g) * 16;
    bf16x8 w0, w1;
    #pragma unroll
    for (int j = 0; j < 8; ++j) { w0[j] = rne_bf16(p[j]); w1[j] = rne_bf16(p[8+j]); }
    *(bf16x8*)&outd[base]     = w0;
    *(bf16x8*)&outd[base + 8] = w1;

    if (qside) {
        float v0 = vw[4*g], v1 = vw[4*g+1], v2 = vw[4*g+2], v3 = vw[4*g+3];
        float sall = v0 + v1 + v2 + v3;
        float c[16];
        c[0]=sall;      c[1]=sall-v0;      c[2]=sall-v1;      c[3]=c[1]-v1;
        c[4]=sall-v2;   c[5]=c[1]-v2;      c[6]=c[2]-v2;      c[7]=c[3]-v2;
        c[8]=sall-v3;   c[9]=c[1]-v3;      c[10]=c[2]-v3;     c[11]=c[3]-v3;
        c[12]=c[4]-v3;  c[13]=c[5]-v3;     c[14]=c[6]-v3;     c[15]=0.f;
        bf16x8 n0, n1;
        #pragma unroll
        for (int j = 0; j < 8; ++j) { n0[j] = rne_bf16(c[j]*p[j]); n1[j] = rne_bf16(c[8+j]*p[8+j]); }
        *(bf16x8*)&outn[base]     = n0;
        *(bf16x8*)&outn[base + 8] = n1;
    }
}

#define MERGE(NA, DA, NQ, DQ) { f32x4 _t = (NQ) * (DA); (NA) = (NA) * (DQ) + _t; (DA) = (DA) * (DQ); }

// -------- scores via MFMA: 32q x 32k per block, 8 waves x 8 quads each --------
// Per quad: den/num inner products (K=16, zero-padded to 32) for 2x2 subtiles.
// Linear merge of 4 quads over common denominator (den16 f32-safe), 1 rcp per hex.
// Cross-wave f32 add via LDS.
__global__ __launch_bounds__(512, 2) void scores_kernel(
    const unsigned short* __restrict__ phid, const unsigned short* __restrict__ phin,
    const unsigned short* __restrict__ psi,  const float* __restrict__ vw,
    float* __restrict__ out)
{
    __shared__ float red[8][64][17];
    __shared__ float vsum_s;
    const int qb = blockIdx.y, kb = blockIdx.x;
    const int tid = threadIdx.x;
    const int w = tid >> 6, l = tid & 63, lg = l >> 4, lr = l & 15;

    if (tid < 64) {
        float4 vv = *(const float4*)&vw[tid * 4];
        float s = vv.x + vv.y + vv.z + vv.w;
        #pragma unroll
        for (int m = 1; m < 64; m <<= 1) s += __shfl_xor(s, m);
        if (tid == 0) vsum_s = s;
    }

    const int q0 = qb * 32 + lr, q1 = q0 + 16;
    const int k0 = kb * 32 + lr, k1 = k0 + 16;
    const bool ld = (lg < 2);
    const int so = lg * 8;
    const f32x4 z = {0.f, 0.f, 0.f, 0.f};
    const bf16x8 zb = {0,0,0,0,0,0,0,0};

    f32x4 a00 = z, a01 = z, a10 = z, a11 = z;   // accS[rh][ch]

    #pragma unroll
    for (int hx = 0; hx < 2; ++hx) {
        f32x4 nA00, nA01, nA10, nA11, dA00, dA01, dA10, dA11;
        #pragma unroll
        for (int qi = 0; qi < 4; ++qi) {
            const int g = w * 8 + hx * 4 + qi;
            bf16x8 afd0 = zb, afd1 = zb, afn0 = zb, afn1 = zb, bp0 = zb, bp1 = zb;
            if (ld) {
                afd0 = *(const bf16x8*)&phid[(q0 * NG + g) * 16 + so];
                afd1 = *(const bf16x8*)&phid[(q1 * NG + g) * 16 + so];
                afn0 = *(const bf16x8*)&phin[(q0 * NG + g) * 16 + so];
                afn1 = *(const bf16x8*)&phin[(q1 * NG + g) * 16 + so];
                bp0  = *(const bf16x8*)&psi [(k0 * NG + g) * 16 + so];
                bp1  = *(const bf16x8*)&psi [(k1 * NG + g) * 16 + so];
            }
            f32x4 d00 = __builtin_amdgcn_mfma_f32_16x16x32_bf16(afd0, bp0, z, 0, 0, 0);
            f32x4 d01 = __builtin_amdgcn_mfma_f32_16x16x32_bf16(afd0, bp1, z, 0, 0, 0);
            f32x4 d10 = __builtin_amdgcn_mfma_f32_16x16x32_bf16(afd1, bp0, z, 0, 0, 0);
            f32x4 d11 = __builtin_amdgcn_mfma_f32_16x16x32_bf16(afd1, bp1, z, 0, 0, 0);
            f32x4 n00 = __builtin_amdgcn_mfma_f32_16x16x32_bf16(afn0, bp0, z, 0, 0, 0);
            f32x4 n01 = __builtin_amdgcn_mfma_f32_16x16x32_bf16(afn0, bp1, z, 0, 0, 0);
            f32x4 n10 = __builtin_amdgcn_mfma_f32_16x16x32_bf16(afn1, bp0, z, 0, 0, 0);
            f32x4 n11 = __builtin_amdgcn_mfma_f32_16x16x32_bf16(afn1, bp1, z, 0, 0, 0);
            if (qi == 0) {
                nA00 = n00; nA01 = n01; nA10 = n10; nA11 = n11;
                dA00 = d00; dA01 = d01; dA10 = d10; dA11 = d11;
            } else {
                MERGE(nA00, dA00, n00, d00);
                MERGE(nA01, dA01, n01, d01);
                MERGE(nA10, dA10, n10, d10);
                MERGE(nA11, dA11, n11, d11);
            }
        }
        #pragma unroll
        for (int r = 0; r < 4; ++r) {
            a00[r] = fmaf(nA00[r], frcp(dA00[r]), a00[r]);
            a01[r] = fmaf(nA01[r], frcp(dA01[r]), a01[r]);
            a10[r] = fmaf(nA10[r], frcp(dA10[r]), a10[r]);
            a11[r] = fmaf(nA11[r], frcp(dA11[r]), a11[r]);
        }
    }

    // write per-wave partials; slot s = rh*8 + ch*4 + r
    #pragma unroll
    for (int r = 0; r < 4; ++r) {
        red[w][l][0*8 + 0*4 + r] = a00[r];
        red[w][l][0*8 + 1*4 + r] = a01[r];
        red[w][l][1*8 + 0*4 + r] = a10[r];
        red[w][l][1*8 + 1*4 + r] = a11[r];
    }
    __syncthreads();

    const float vsum = vsum_s;
    const int lane = tid & 63, sbase = (tid >> 6) * 2;
    #pragma unroll
    for (int ss = 0; ss < 2; ++ss) {
        const int s = sbase + ss;
        float sum = 0.f;
        #pragma unroll
        for (int ww = 0; ww < 8; ++ww) sum += red[ww][lane][s];
        const int r = s & 3, ch = (s >> 2) & 1, rh = s >> 3;
        const int row = qb * 32 + rh * 16 + (lane >> 4) * 4 + r;
        const int col = kb * 32 + ch * 16 + (lane & 15);
        out[row * TK + col] = fmaf(-2.f, sum, vsum);
    }
}

extern "C" void kernel_launch(void* const* d_in, const int* in_sizes, int n_in,
                              void* d_out, int out_size, void* d_ws, size_t ws_size,
                              hipStream_t stream) {
    const float* query = (const float*)d_in[0];   // [512,256]
    const float* key   = (const float*)d_in[1];   // [1024,256]
    // d_in[2] = value, unused by the reference
    const float* Wq    = (const float*)d_in[3];   // [256,256]
    const float* Wk    = (const float*)d_in[4];   // [256,256]
    const float* vw    = (const float*)d_in[5];   // [1,256]
    float* out = (float*)d_out;                   // [512,1024]

    char* ws = (char*)d_ws;
    float* eqT = (float*)ws;                                  // 256x512 f32  (512 KB)
    float* ekT = (float*)(ws + 524288);                       // 256x1024 f32 (1 MB)
    unsigned short* phid = (unsigned short*)(ws + 1572864);   // 512x64x16 bf16 (1 MB)
    unsigned short* phin = (unsigned short*)(ws + 2621440);   // 512x64x16 bf16 (1 MB)
    unsigned short* psi  = (unsigned short*)(ws + 3670016);   // 1024x64x16 bf16 (2 MB)

    proj_mfma_kernel<<<384, 256, 0, stream>>>(query, key, Wq, Wk, eqT, ekT);
    featurize_kernel<<<dim3(2, NG), 256, 0, stream>>>(eqT, vw, phid, phin, TQ, 1);
    featurize_kernel<<<dim3(4, NG), 256, 0, stream>>>(ekT, vw, psi, nullptr, TK, 0);
    scores_kernel<<<dim3(TK / 32, TQ / 32), 512, 0, stream>>>(phid, phin, psi, vw, out);
}

// Round 13
// 26.796 us; speedup vs baseline: 1.5492x; 1.5492x over previous
//
#include <hip/hip_runtime.h>

#define DD 256
#define TQ 512
#define TK 1024
#define NG 64            // d-quads (256/4)
#define C2 2.88539008177792681472f   // 2*log2(e)

typedef short bf16x8 __attribute__((ext_vector_type(8)));
typedef float f32x4  __attribute__((ext_vector_type(4)));
typedef float f32x16 __attribute__((ext_vector_type(16)));

__device__ __forceinline__ float fexp2(float x){ return __builtin_amdgcn_exp2f(x); }
__device__ __forceinline__ float frcp (float x){ return __builtin_amdgcn_rcpf(x); }
__device__ __forceinline__ short rne_bf16(float x){
    union { float f; unsigned u; } v; v.f = x;
    unsigned r = v.u + 0x7FFFu + ((v.u >> 16) & 1u);
    return (short)(r >> 16);
}

// -------- proj via MFMA (validated 16x16x32 layout), storing TRANSPOSED E --------
// EqT[d][q] (512-stride), EkT[d][k] (1024-stride); E = exp2(C2 * (X @ W^T))
__global__ __launch_bounds__(256) void proj_mfma_kernel(
    const float* __restrict__ query, const float* __restrict__ key,
    const float* __restrict__ Wq, const float* __restrict__ Wk,
    float* __restrict__ eqT, float* __restrict__ ekT)
{
    const int w = threadIdx.x >> 6, l = threadIdx.x & 63;
    int i = blockIdx.x * 4 + w;
    const float* X; const float* W; float* outT; int NT;
    if (i < 512) { X = query; W = Wq; outT = eqT; NT = TQ; }
    else { i -= 512; X = key; W = Wk; outT = ekT; NT = TK; }
    const int rt = i >> 4, ct = i & 15;
    const int lr = l & 15, kg = (l >> 4) * 8;
    const float* Xp = X + (rt * 16 + lr) * DD + kg;
    const float* Wp = W + (ct * 16 + lr) * DD + kg;

    f32x4 acc = {0.f, 0.f, 0.f, 0.f};
    #pragma unroll
    for (int k0 = 0; k0 < DD; k0 += 32) {
        float4 xa = *(const float4*)&Xp[k0];
        float4 xb = *(const float4*)&Xp[k0 + 4];
        float4 wa = *(const float4*)&Wp[k0];
        float4 wb = *(const float4*)&Wp[k0 + 4];
        bf16x8 af, bf;
        af[0] = rne_bf16(xa.x); af[1] = rne_bf16(xa.y);
        af[2] = rne_bf16(xa.z); af[3] = rne_bf16(xa.w);
        af[4] = rne_bf16(xb.x); af[5] = rne_bf16(xb.y);
        af[6] = rne_bf16(xb.z); af[7] = rne_bf16(xb.w);
        bf[0] = rne_bf16(wa.x); bf[1] = rne_bf16(wa.y);
        bf[2] = rne_bf16(wa.z); bf[3] = rne_bf16(wa.w);
        bf[4] = rne_bf16(wb.x); bf[5] = rne_bf16(wb.y);
        bf[6] = rne_bf16(wb.z); bf[7] = rne_bf16(wb.w);
        acc = __builtin_amdgcn_mfma_f32_16x16x32_bf16(af, bf, acc, 0, 0, 0);
    }
    const int orow = rt * 16 + (l >> 4) * 4;   // token
    const int ocol = ct * 16 + lr;             // d
    float4 st = make_float4(fexp2(C2 * acc[0]), fexp2(C2 * acc[1]),
                            fexp2(C2 * acc[2]), fexp2(C2 * acc[3]));
    *(float4*)&outT[ocol * NT + orow] = st;
}

// -------- featurize: per (token, quad g) build 16 subset-product features --------
// g-MAJOR layout: out[(g*NT + token)*16 + S]  (coalesced fragment loads in scores).
// q-side also writes c_S * p_S with c_S = sum_{j not in S} v[4g+j].
__global__ __launch_bounds__(256) void featurize_kernel(
    const float* __restrict__ eqT, const float* __restrict__ ekT,
    const float* __restrict__ vw,
    unsigned short* __restrict__ phid, unsigned short* __restrict__ phin,
    unsigned short* __restrict__ psi)
{
    const int bx = blockIdx.x, g = blockIdx.y;
    const int qside = (bx < 2);
    const float* ET; unsigned short* outd; int NT, token;
    if (qside) { ET = eqT; NT = TQ; token = bx * 256 + threadIdx.x; outd = phid; }
    else       { ET = ekT; NT = TK; token = (bx - 2) * 256 + threadIdx.x; outd = psi; }

    float E0 = ET[(4*g+0)*NT + token];
    float E1 = ET[(4*g+1)*NT + token];
    float E2 = ET[(4*g+2)*NT + token];
    float E3 = ET[(4*g+3)*NT + token];
    float p[16];
    p[0]=1.f;   p[1]=E0;      p[2]=E1;      p[3]=E0*E1;
    p[4]=E2;    p[5]=E0*E2;   p[6]=E1*E2;   p[7]=p[3]*E2;
    p[8]=E3;    p[9]=E0*E3;   p[10]=E1*E3;  p[11]=p[3]*E3;
    p[12]=E2*E3;p[13]=p[5]*E3;p[14]=p[6]*E3;p[15]=p[7]*E3;

    const int base = (g * NT + token) * 16;
    bf16x8 w0, w1;
    #pragma unroll
    for (int j = 0; j < 8; ++j) { w0[j] = rne_bf16(p[j]); w1[j] = rne_bf16(p[8+j]); }
    *(bf16x8*)&outd[base]     = w0;
    *(bf16x8*)&outd[base + 8] = w1;

    if (qside) {
        float v0 = vw[4*g], v1 = vw[4*g+1], v2 = vw[4*g+2], v3 = vw[4*g+3];
        float sall = v0 + v1 + v2 + v3;
        float c[16];
        c[0]=sall;      c[1]=sall-v0;      c[2]=sall-v1;      c[3]=c[1]-v1;
        c[4]=sall-v2;   c[5]=c[1]-v2;      c[6]=c[2]-v2;      c[7]=c[3]-v2;
        c[8]=sall-v3;   c[9]=c[1]-v3;      c[10]=c[2]-v3;     c[11]=c[3]-v3;
        c[12]=c[4]-v3;  c[13]=c[5]-v3;     c[14]=c[6]-v3;     c[15]=0.f;
        bf16x8 n0, n1;
        #pragma unroll
        for (int j = 0; j < 8; ++j) { n0[j] = rne_bf16(c[j]*p[j]); n1[j] = rne_bf16(c[8+j]*p[8+j]); }
        *(bf16x8*)&phin[base]     = n0;
        *(bf16x8*)&phin[base + 8] = n1;
    }
}

#define MERGE16(NA, DA, NQ, DQ) { f32x16 _t = (NQ) * (DA); (NA) = (NA) * (DQ) + _t; (DA) = (DA) * (DQ); }

// -------- scores via 32x32x16 MFMA: 32q x 32k per block, 8 waves x 8 quads --------
// Per quad: den/num K=16 inner products (exact, no zero-pad), 1 wave = full 32x32.
// A-frag: lane row=l&31 (q-token), k=(l>>5)*8+j (feature S). B: col=l&31 (k-token).
// C/D: col=lane&31, row=(reg&3)+8*(reg>>2)+4*(lane>>5)  [m74/m101].
// Merge 4 quads over common denominator, 1 rcp per 16 d; cross-wave reduce in LDS.
__global__ __launch_bounds__(512, 2) void scores_kernel(
    const unsigned short* __restrict__ phid, const unsigned short* __restrict__ phin,
    const unsigned short* __restrict__ psi,  const float* __restrict__ vw,
    float* __restrict__ out)
{
    __shared__ float red[8][64][17];
    __shared__ float vsum_s;
    const int qb = blockIdx.y, kb = blockIdx.x;
    const int tid = threadIdx.x;
    const int w = tid >> 6, l = tid & 63, lr31 = l & 31, lh = l >> 5;

    if (tid < 64) {
        float4 vv = *(const float4*)&vw[tid * 4];
        float s = vv.x + vv.y + vv.z + vv.w;
        #pragma unroll
        for (int m = 1; m < 64; m <<= 1) s += __shfl_xor(s, m);
        if (tid == 0) vsum_s = s;
    }

    const int qt = qb * 32 + lr31;     // A row token
    const int kt = kb * 32 + lr31;     // B col token
    const int fo = lh * 8;             // feature offset
    const f32x16 z = {0.f,0.f,0.f,0.f,0.f,0.f,0.f,0.f,0.f,0.f,0.f,0.f,0.f,0.f,0.f,0.f};

    f32x16 a = z;
    #pragma unroll
    for (int hx = 0; hx < 2; ++hx) {
        f32x16 nA, dA;
        #pragma unroll
        for (int qi = 0; qi < 4; ++qi) {
            const int g = w * 8 + hx * 4 + qi;
            bf16x8 afd = *(const bf16x8*)&phid[(g * TQ + qt) * 16 + fo];
            bf16x8 afn = *(const bf16x8*)&phin[(g * TQ + qt) * 16 + fo];
            bf16x8 bp  = *(const bf16x8*)&psi [(g * TK + kt) * 16 + fo];
            f32x16 d = __builtin_amdgcn_mfma_f32_32x32x16_bf16(afd, bp, z, 0, 0, 0);
            f32x16 n = __builtin_amdgcn_mfma_f32_32x32x16_bf16(afn, bp, z, 0, 0, 0);
            if (qi == 0) { nA = n; dA = d; }
            else MERGE16(nA, dA, n, d);
        }
        #pragma unroll
        for (int r = 0; r < 16; ++r)
            a[r] = fmaf(nA[r], frcp(dA[r]), a[r]);
    }

    #pragma unroll
    for (int r = 0; r < 16; ++r) red[w][l][r] = a[r];
    __syncthreads();

    const float vsum = vsum_s;
    const int lane = tid & 63, rbase = (tid >> 6) * 2;
    const int lane_lh = lane >> 5, lane_lr = lane & 31;
    #pragma unroll
    for (int rr = 0; rr < 2; ++rr) {
        const int r = rbase + rr;
        float sum = 0.f;
        #pragma unroll
        for (int ww = 0; ww < 8; ++ww) sum += red[ww][lane][r];
        const int row = qb * 32 + (r & 3) + 8 * (r >> 2) + 4 * lane_lh;
        const int col = kb * 32 + lane_lr;
        out[row * TK + col] = fmaf(-2.f, sum, vsum);
    }
}

extern "C" void kernel_launch(void* const* d_in, const int* in_sizes, int n_in,
                              void* d_out, int out_size, void* d_ws, size_t ws_size,
                              hipStream_t stream) {
    const float* query = (const float*)d_in[0];   // [512,256]
    const float* key   = (const float*)d_in[1];   // [1024,256]
    // d_in[2] = value, unused by the reference
    const float* Wq    = (const float*)d_in[3];   // [256,256]
    const float* Wk    = (const float*)d_in[4];   // [256,256]
    const float* vw    = (const float*)d_in[5];   // [1,256]
    float* out = (float*)d_out;                   // [512,1024]

    char* ws = (char*)d_ws;
    float* eqT = (float*)ws;                                  // 256x512 f32  (512 KB)
    float* ekT = (float*)(ws + 524288);                       // 256x1024 f32 (1 MB)
    unsigned short* phid = (unsigned short*)(ws + 1572864);   // 64x512x16 bf16 (1 MB)
    unsigned short* phin = (unsigned short*)(ws + 2621440);   // 64x512x16 bf16 (1 MB)
    unsigned short* psi  = (unsigned short*)(ws + 3670016);   // 64x1024x16 bf16 (2 MB)

    proj_mfma_kernel<<<384, 256, 0, stream>>>(query, key, Wq, Wk, eqT, ekT);
    featurize_kernel<<<dim3(6, NG), 256, 0, stream>>>(eqT, ekT, vw, phid, phin, psi);
    scores_kernel<<<dim3(TK / 32, TQ / 32), 512, 0, stream>>>(phid, phin, psi, vw, out);
}

// Round 14
// 26.680 us; speedup vs baseline: 1.5560x; 1.0044x over previous
//
#include <hip/hip_runtime.h>

#define DD 256
#define TQ 512
#define TK 1024
#define NG 64            // d-quads (256/4)
#define C2 2.88539008177792681472f   // 2*log2(e)

typedef short bf16x8 __attribute__((ext_vector_type(8)));
typedef float f32x4  __attribute__((ext_vector_type(4)));
typedef float f32x16 __attribute__((ext_vector_type(16)));

__device__ __forceinline__ float fexp2(float x){ return __builtin_amdgcn_exp2f(x); }
__device__ __forceinline__ float frcp (float x){ return __builtin_amdgcn_rcpf(x); }
__device__ __forceinline__ short rne_bf16(float x){
    union { float f; unsigned u; } v; v.f = x;
    unsigned r = v.u + 0x7FFFu + ((v.u >> 16) & 1u);
    return (short)(r >> 16);
}

// -------- proj via MFMA (validated 16x16x32 layout), storing TRANSPOSED E --------
// EqT[d][q] (512-stride), EkT[d][k] (1024-stride); E = exp2(C2 * (X @ W^T))
__global__ __launch_bounds__(256) void proj_mfma_kernel(
    const float* __restrict__ query, const float* __restrict__ key,
    const float* __restrict__ Wq, const float* __restrict__ Wk,
    float* __restrict__ eqT, float* __restrict__ ekT)
{
    const int w = threadIdx.x >> 6, l = threadIdx.x & 63;
    int i = blockIdx.x * 4 + w;
    const float* X; const float* W; float* outT; int NT;
    if (i < 512) { X = query; W = Wq; outT = eqT; NT = TQ; }
    else { i -= 512; X = key; W = Wk; outT = ekT; NT = TK; }
    const int rt = i >> 4, ct = i & 15;
    const int lr = l & 15, kg = (l >> 4) * 8;
    const float* Xp = X + (rt * 16 + lr) * DD + kg;
    const float* Wp = W + (ct * 16 + lr) * DD + kg;

    f32x4 acc = {0.f, 0.f, 0.f, 0.f};
    #pragma unroll
    for (int k0 = 0; k0 < DD; k0 += 32) {
        float4 xa = *(const float4*)&Xp[k0];
        float4 xb = *(const float4*)&Xp[k0 + 4];
        float4 wa = *(const float4*)&Wp[k0];
        float4 wb = *(const float4*)&Wp[k0 + 4];
        bf16x8 af, bf;
        af[0] = rne_bf16(xa.x); af[1] = rne_bf16(xa.y);
        af[2] = rne_bf16(xa.z); af[3] = rne_bf16(xa.w);
        af[4] = rne_bf16(xb.x); af[5] = rne_bf16(xb.y);
        af[6] = rne_bf16(xb.z); af[7] = rne_bf16(xb.w);
        bf[0] = rne_bf16(wa.x); bf[1] = rne_bf16(wa.y);
        bf[2] = rne_bf16(wa.z); bf[3] = rne_bf16(wa.w);
        bf[4] = rne_bf16(wb.x); bf[5] = rne_bf16(wb.y);
        bf[6] = rne_bf16(wb.z); bf[7] = rne_bf16(wb.w);
        acc = __builtin_amdgcn_mfma_f32_16x16x32_bf16(af, bf, acc, 0, 0, 0);
    }
    const int orow = rt * 16 + (l >> 4) * 4;   // token
    const int ocol = ct * 16 + lr;             // d
    float4 st = make_float4(fexp2(C2 * acc[0]), fexp2(C2 * acc[1]),
                            fexp2(C2 * acc[2]), fexp2(C2 * acc[3]));
    *(float4*)&outT[ocol * NT + orow] = st;
}

// -------- featurize: per (token, quad g) build 16 subset-product features --------
// g-MAJOR layout: out[(g*NT + token)*16 + S]  (coalesced fragment loads in scores).
// q-side also writes c_S * p_S with c_S = sum_{j not in S} v[4g+j].
__global__ __launch_bounds__(256) void featurize_kernel(
    const float* __restrict__ eqT, const float* __restrict__ ekT,
    const float* __restrict__ vw,
    unsigned short* __restrict__ phid, unsigned short* __restrict__ phin,
    unsigned short* __restrict__ psi)
{
    const int bx = blockIdx.x, g = blockIdx.y;
    const int qside = (bx < 2);
    const float* ET; unsigned short* outd; int NT, token;
    if (qside) { ET = eqT; NT = TQ; token = bx * 256 + threadIdx.x; outd = phid; }
    else       { ET = ekT; NT = TK; token = (bx - 2) * 256 + threadIdx.x; outd = psi; }

    float E0 = ET[(4*g+0)*NT + token];
    float E1 = ET[(4*g+1)*NT + token];
    float E2 = ET[(4*g+2)*NT + token];
    float E3 = ET[(4*g+3)*NT + token];
    float p[16];
    p[0]=1.f;   p[1]=E0;      p[2]=E1;      p[3]=E0*E1;
    p[4]=E2;    p[5]=E0*E2;   p[6]=E1*E2;   p[7]=p[3]*E2;
    p[8]=E3;    p[9]=E0*E3;   p[10]=E1*E3;  p[11]=p[3]*E3;
    p[12]=E2*E3;p[13]=p[5]*E3;p[14]=p[6]*E3;p[15]=p[7]*E3;

    const int base = (g * NT + token) * 16;
    bf16x8 w0, w1;
    #pragma unroll
    for (int j = 0; j < 8; ++j) { w0[j] = rne_bf16(p[j]); w1[j] = rne_bf16(p[8+j]); }
    *(bf16x8*)&outd[base]     = w0;
    *(bf16x8*)&outd[base + 8] = w1;

    if (qside) {
        float v0 = vw[4*g], v1 = vw[4*g+1], v2 = vw[4*g+2], v3 = vw[4*g+3];
        float sall = v0 + v1 + v2 + v3;
        float c[16];
        c[0]=sall;      c[1]=sall-v0;      c[2]=sall-v1;      c[3]=c[1]-v1;
        c[4]=sall-v2;   c[5]=c[1]-v2;      c[6]=c[2]-v2;      c[7]=c[3]-v2;
        c[8]=sall-v3;   c[9]=c[1]-v3;      c[10]=c[2]-v3;     c[11]=c[3]-v3;
        c[12]=c[4]-v3;  c[13]=c[5]-v3;     c[14]=c[6]-v3;     c[15]=0.f;
        bf16x8 n0, n1;
        #pragma unroll
        for (int j = 0; j < 8; ++j) { n0[j] = rne_bf16(c[j]*p[j]); n1[j] = rne_bf16(c[8+j]*p[8+j]); }
        *(bf16x8*)&phin[base]     = n0;
        *(bf16x8*)&phin[base + 8] = n1;
    }
}

#define MERGE16(NA, DA, NQ, DQ) { f32x16 _t = (NQ) * (DA); (NA) = (NA) * (DQ) + _t; (DA) = (DA) * (DQ); }

// -------- scores via 32x32x16 MFMA: 32q x 32k per block, 8 waves x 8 quads --------
// XCD-locality swizzle: id = qb%8 + 8*kb + 256*(qb/8)  (bijective, 512 blocks).
// Round-robin id->XCD means all 32 kb-blocks of a qb share an XCD: per-XCD L2
// working set = 2 qb-rows of q-features (256KB) + psi (2MB) < 4MB -> L2-resident.
__global__ __launch_bounds__(512, 2) void scores_kernel(
    const unsigned short* __restrict__ phid, const unsigned short* __restrict__ phin,
    const unsigned short* __restrict__ psi,  const float* __restrict__ vw,
    float* __restrict__ out)
{
    __shared__ float red[8][64][17];
    __shared__ float vsum_s;
    const int id = blockIdx.x;
    const int qb = (id & 7) + 8 * (id >> 8);
    const int kb = (id >> 3) & 31;
    const int tid = threadIdx.x;
    const int w = tid >> 6, l = tid & 63, lr31 = l & 31, lh = l >> 5;

    if (tid < 64) {
        float4 vv = *(const float4*)&vw[tid * 4];
        float s = vv.x + vv.y + vv.z + vv.w;
        #pragma unroll
        for (int m = 1; m < 64; m <<= 1) s += __shfl_xor(s, m);
        if (tid == 0) vsum_s = s;
    }

    const int qt = qb * 32 + lr31;     // A row token
    const int kt = kb * 32 + lr31;     // B col token
    const int fo = lh * 8;             // feature offset
    const f32x16 z = {0.f,0.f,0.f,0.f,0.f,0.f,0.f,0.f,0.f,0.f,0.f,0.f,0.f,0.f,0.f,0.f};

    f32x16 a = z;
    #pragma unroll
    for (int hx = 0; hx < 2; ++hx) {
        f32x16 nA, dA;
        #pragma unroll
        for (int qi = 0; qi < 4; ++qi) {
            const int g = w * 8 + hx * 4 + qi;
            bf16x8 afd = *(const bf16x8*)&phid[(g * TQ + qt) * 16 + fo];
            bf16x8 afn = *(const bf16x8*)&phin[(g * TQ + qt) * 16 + fo];
            bf16x8 bp  = *(const bf16x8*)&psi [(g * TK + kt) * 16 + fo];
            f32x16 d = __builtin_amdgcn_mfma_f32_32x32x16_bf16(afd, bp, z, 0, 0, 0);
            f32x16 n = __builtin_amdgcn_mfma_f32_32x32x16_bf16(afn, bp, z, 0, 0, 0);
            if (qi == 0) { nA = n; dA = d; }
            else MERGE16(nA, dA, n, d);
        }
        #pragma unroll
        for (int r = 0; r < 16; ++r)
            a[r] = fmaf(nA[r], frcp(dA[r]), a[r]);
    }

    #pragma unroll
    for (int r = 0; r < 16; ++r) red[w][l][r] = a[r];
    __syncthreads();

    const float vsum = vsum_s;
    const int lane = tid & 63, rbase = (tid >> 6) * 2;
    const int lane_lh = lane >> 5, lane_lr = lane & 31;
    #pragma unroll
    for (int rr = 0; rr < 2; ++rr) {
        const int r = rbase + rr;
        float sum = 0.f;
        #pragma unroll
        for (int ww = 0; ww < 8; ++ww) sum += red[ww][lane][r];
        const int row = qb * 32 + (r & 3) + 8 * (r >> 2) + 4 * lane_lh;
        const int col = kb * 32 + lane_lr;
        out[row * TK + col] = fmaf(-2.f, sum, vsum);
    }
}

extern "C" void kernel_launch(void* const* d_in, const int* in_sizes, int n_in,
                              void* d_out, int out_size, void* d_ws, size_t ws_size,
                              hipStream_t stream) {
    const float* query = (const float*)d_in[0];   // [512,256]
    const float* key   = (const float*)d_in[1];   // [1024,256]
    // d_in[2] = value, unused by the reference
    const float* Wq    = (const float*)d_in[3];   // [256,256]
    const float* Wk    = (const float*)d_in[4];   // [256,256]
    const float* vw    = (const float*)d_in[5];   // [1,256]
    float* out = (float*)d_out;                   // [512,1024]

    char* ws = (char*)d_ws;
    float* eqT = (float*)ws;                                  // 256x512 f32  (512 KB)
    float* ekT = (float*)(ws + 524288);                       // 256x1024 f32 (1 MB)
    unsigned short* phid = (unsigned short*)(ws + 1572864);   // 64x512x16 bf16 (1 MB)
    unsigned short* phin = (unsigned short*)(ws + 2621440);   // 64x512x16 bf16 (1 MB)
    unsigned short* psi  = (unsigned short*)(ws + 3670016);   // 64x1024x16 bf16 (2 MB)

    proj_mfma_kernel<<<384, 256, 0, stream>>>(query, key, Wq, Wk, eqT, ekT);
    featurize_kernel<<<dim3(6, NG), 256, 0, stream>>>(eqT, ekT, vw, phid, phin, psi);
    scores_kernel<<<512, 512, 0, stream>>>(phid, phin, psi, vw, out);
}

// Round 15
// 24.345 us; speedup vs baseline: 1.7052x; 1.0959x over previous
//
#include <hip/hip_runtime.h>

#define DD 256
#define TQ 512
#define TK 1024
#define NG 64            // d-quads (256/4)
#define C2 2.88539008177792681472f   // 2*log2(e)

typedef short bf16x8 __attribute__((ext_vector_type(8)));
typedef float f32x4  __attribute__((ext_vector_type(4)));
typedef float f32x16 __attribute__((ext_vector_type(16)));

__device__ __forceinline__ float fexp2(float x){ return __builtin_amdgcn_exp2f(x); }
__device__ __forceinline__ float frcp (float x){ return __builtin_amdgcn_rcpf(x); }
__device__ __forceinline__ short rne_bf16(float x){
    union { float f; unsigned u; } v; v.f = x;
    unsigned r = v.u + 0x7FFFu + ((v.u >> 16) & 1u);
    return (short)(r >> 16);
}

// -------- proj + featurize fused --------
// Per wave: one 16x16 E-tile via MFMA (validated 16x16x32 layout), exp2, bounce
// through per-wave LDS (stride 21: write/read conflicts <= 2-3 way), then each
// lane builds the 16 subset-product features for one (token, quad) pair and
// writes phid/phin (q-side) or psi (k-side) directly. g-major feature layout.
__global__ __launch_bounds__(256) void proj_feat_kernel(
    const float* __restrict__ query, const float* __restrict__ key,
    const float* __restrict__ Wq, const float* __restrict__ Wk,
    const float* __restrict__ vw,
    unsigned short* __restrict__ phid, unsigned short* __restrict__ phin,
    unsigned short* __restrict__ psi)
{
    __shared__ float et[4][16][21];     // [wave][d_local][token_local(+pad)]
    const int w = threadIdx.x >> 6, l = threadIdx.x & 63;
    int i = blockIdx.x * 4 + w;
    const float* X; const float* W; unsigned short* outd; int NT, qside;
    if (i < 512) { X = query; W = Wq; outd = phid; NT = TQ; qside = 1; }
    else { i -= 512; X = key; W = Wk; outd = psi; NT = TK; qside = 0; }
    const int rt = i >> 4, ct = i & 15;
    const int lr = l & 15, kg = (l >> 4) * 8;
    const float* Xp = X + (rt * 16 + lr) * DD + kg;
    const float* Wp = W + (ct * 16 + lr) * DD + kg;

    f32x4 acc = {0.f, 0.f, 0.f, 0.f};
    #pragma unroll
    for (int k0 = 0; k0 < DD; k0 += 32) {
        float4 xa = *(const float4*)&Xp[k0];
        float4 xb = *(const float4*)&Xp[k0 + 4];
        float4 wa = *(const float4*)&Wp[k0];
        float4 wb = *(const float4*)&Wp[k0 + 4];
        bf16x8 af, bf;
        af[0] = rne_bf16(xa.x); af[1] = rne_bf16(xa.y);
        af[2] = rne_bf16(xa.z); af[3] = rne_bf16(xa.w);
        af[4] = rne_bf16(xb.x); af[5] = rne_bf16(xb.y);
        af[6] = rne_bf16(xb.z); af[7] = rne_bf16(xb.w);
        bf[0] = rne_bf16(wa.x); bf[1] = rne_bf16(wa.y);
        bf[2] = rne_bf16(wa.z); bf[3] = rne_bf16(wa.w);
        bf[4] = rne_bf16(wb.x); bf[5] = rne_bf16(wb.y);
        bf[6] = rne_bf16(wb.z); bf[7] = rne_bf16(wb.w);
        acc = __builtin_amdgcn_mfma_f32_16x16x32_bf16(af, bf, acc, 0, 0, 0);
    }

    // E-tile to per-wave LDS: C row = token_local (l>>4)*4+r, col = d_local lr
    #pragma unroll
    for (int r = 0; r < 4; ++r)
        et[w][lr][(l >> 4) * 4 + r] = fexp2(C2 * acc[r]);
    // (same-wave ds_write -> ds_read; compiler inserts lgkmcnt wait)

    // featurize: lane = (token_local tl, quad_local gq)
    const int tl = l & 15, gq = l >> 4;
    float E0 = et[w][gq * 4 + 0][tl];
    float E1 = et[w][gq * 4 + 1][tl];
    float E2 = et[w][gq * 4 + 2][tl];
    float E3 = et[w][gq * 4 + 3][tl];
    float p[16];
    p[0]=1.f;   p[1]=E0;      p[2]=E1;      p[3]=E0*E1;
    p[4]=E2;    p[5]=E0*E2;   p[6]=E1*E2;   p[7]=p[3]*E2;
    p[8]=E3;    p[9]=E0*E3;   p[10]=E1*E3;  p[11]=p[3]*E3;
    p[12]=E2*E3;p[13]=p[5]*E3;p[14]=p[6]*E3;p[15]=p[7]*E3;

    const int g = ct * 4 + gq;
    const int token = rt * 16 + tl;
    const int base = (g * NT + token) * 16;
    bf16x8 w0, w1;
    #pragma unroll
    for (int j = 0; j < 8; ++j) { w0[j] = rne_bf16(p[j]); w1[j] = rne_bf16(p[8+j]); }
    *(bf16x8*)&outd[base]     = w0;
    *(bf16x8*)&outd[base + 8] = w1;

    if (qside) {
        float4 v4 = *(const float4*)&vw[4 * g];
        float v0 = v4.x, v1 = v4.y, v2 = v4.z, v3 = v4.w;
        float sall = v0 + v1 + v2 + v3;
        float c[16];
        c[0]=sall;      c[1]=sall-v0;      c[2]=sall-v1;      c[3]=c[1]-v1;
        c[4]=sall-v2;   c[5]=c[1]-v2;      c[6]=c[2]-v2;      c[7]=c[3]-v2;
        c[8]=sall-v3;   c[9]=c[1]-v3;      c[10]=c[2]-v3;     c[11]=c[3]-v3;
        c[12]=c[4]-v3;  c[13]=c[5]-v3;     c[14]=c[6]-v3;     c[15]=0.f;
        bf16x8 n0, n1;
        #pragma unroll
        for (int j = 0; j < 8; ++j) { n0[j] = rne_bf16(c[j]*p[j]); n1[j] = rne_bf16(c[8+j]*p[8+j]); }
        *(bf16x8*)&phin[base]     = n0;
        *(bf16x8*)&phin[base + 8] = n1;
    }
}

#define MERGE16(NA, DA, NQ, DQ) { f32x16 _t = (NQ) * (DA); (NA) = (NA) * (DQ) + _t; (DA) = (DA) * (DQ); }

// -------- scores via 32x32x16 MFMA: 32q x 32k per block, 8 waves x 8 quads --------
// (unchanged from R14)
__global__ __launch_bounds__(512, 2) void scores_kernel(
    const unsigned short* __restrict__ phid, const unsigned short* __restrict__ phin,
    const unsigned short* __restrict__ psi,  const float* __restrict__ vw,
    float* __restrict__ out)
{
    __shared__ float red[8][64][17];
    __shared__ float vsum_s;
    const int id = blockIdx.x;
    const int qb = (id & 7) + 8 * (id >> 8);
    const int kb = (id >> 3) & 31;
    const int tid = threadIdx.x;
    const int w = tid >> 6, l = tid & 63, lr31 = l & 31, lh = l >> 5;

    if (tid < 64) {
        float4 vv = *(const float4*)&vw[tid * 4];
        float s = vv.x + vv.y + vv.z + vv.w;
        #pragma unroll
        for (int m = 1; m < 64; m <<= 1) s += __shfl_xor(s, m);
        if (tid == 0) vsum_s = s;
    }

    const int qt = qb * 32 + lr31;     // A row token
    const int kt = kb * 32 + lr31;     // B col token
    const int fo = lh * 8;             // feature offset
    const f32x16 z = {0.f,0.f,0.f,0.f,0.f,0.f,0.f,0.f,0.f,0.f,0.f,0.f,0.f,0.f,0.f,0.f};

    f32x16 a = z;
    #pragma unroll
    for (int hx = 0; hx < 2; ++hx) {
        f32x16 nA, dA;
        #pragma unroll
        for (int qi = 0; qi < 4; ++qi) {
            const int g = w * 8 + hx * 4 + qi;
            bf16x8 afd = *(const bf16x8*)&phid[(g * TQ + qt) * 16 + fo];
            bf16x8 afn = *(const bf16x8*)&phin[(g * TQ + qt) * 16 + fo];
            bf16x8 bp  = *(const bf16x8*)&psi [(g * TK + kt) * 16 + fo];
            f32x16 d = __builtin_amdgcn_mfma_f32_32x32x16_bf16(afd, bp, z, 0, 0, 0);
            f32x16 n = __builtin_amdgcn_mfma_f32_32x32x16_bf16(afn, bp, z, 0, 0, 0);
            if (qi == 0) { nA = n; dA = d; }
            else MERGE16(nA, dA, n, d);
        }
        #pragma unroll
        for (int r = 0; r < 16; ++r)
            a[r] = fmaf(nA[r], frcp(dA[r]), a[r]);
    }

    #pragma unroll
    for (int r = 0; r < 16; ++r) red[w][l][r] = a[r];
    __syncthreads();

    const float vsum = vsum_s;
    const int lane = tid & 63, rbase = (tid >> 6) * 2;
    const int lane_lh = lane >> 5, lane_lr = lane & 31;
    #pragma unroll
    for (int rr = 0; rr < 2; ++rr) {
        const int r = rbase + rr;
        float sum = 0.f;
        #pragma unroll
        for (int ww = 0; ww < 8; ++ww) sum += red[ww][lane][r];
        const int row = qb * 32 + (r & 3) + 8 * (r >> 2) + 4 * lane_lh;
        const int col = kb * 32 + lane_lr;
        out[row * TK + col] = fmaf(-2.f, sum, vsum);
    }
}

extern "C" void kernel_launch(void* const* d_in, const int* in_sizes, int n_in,
                              void* d_out, int out_size, void* d_ws, size_t ws_size,
                              hipStream_t stream) {
    const float* query = (const float*)d_in[0];   // [512,256]
    const float* key   = (const float*)d_in[1];   // [1024,256]
    // d_in[2] = value, unused by the reference
    const float* Wq    = (const float*)d_in[3];   // [256,256]
    const float* Wk    = (const float*)d_in[4];   // [256,256]
    const float* vw    = (const float*)d_in[5];   // [1,256]
    float* out = (float*)d_out;                   // [512,1024]

    char* ws = (char*)d_ws;
    unsigned short* phid = (unsigned short*)ws;               // 64x512x16 bf16 (1 MB)
    unsigned short* phin = (unsigned short*)(ws + 1048576);   // 64x512x16 bf16 (1 MB)
    unsigned short* psi  = (unsigned short*)(ws + 2097152);   // 64x1024x16 bf16 (2 MB)

    proj_feat_kernel<<<384, 256, 0, stream>>>(query, key, Wq, Wk, vw, phid, phin, psi);
    scores_kernel<<<512, 512, 0, stream>>>(phid, phin, psi, vw, out);
}